// Round 3
// baseline (5407.541 us; speedup 1.0000x reference)
//
#include <hip/hip_runtime.h>
#include <math.h>

#define HD 50
#define HP 52          // padded LDS row stride (52*4 = 208 B, 16B-aligned, 13 x b128)
#define TT 512
#define BR 16          // batch rows per block -> 256 blocks = 1 per CU, single pass
#define TC 64          // timestep chunk for x prefetch

__device__ __forceinline__ float sigf(float x) {
    return 1.0f / (1.0f + __expf(-x));
}
__device__ __forceinline__ float tanhfast(float x) {
    return 1.0f - 2.0f / (__expf(2.0f * x) + 1.0f);
}

// 8 waves: waves 0-3 = layer-0 gates (step t), waves 4-7 = layer-1 gates (step t-1),
// software-pipelined via double-buffered h0. Max 101 weight floats/lane -> VGPR-resident
// under the 256-VGPR cap of __launch_bounds__(512,2): no AGPR/scratch round-trips.
__global__ __launch_bounds__(512, 2) void lstm2_pipe_kernel(
    const float* __restrict__ x,
    const float* __restrict__ Wih0, const float* __restrict__ Whh0,
    const float* __restrict__ bih0, const float* __restrict__ bhh0,
    const float* __restrict__ Wih1, const float* __restrict__ Whh1,
    const float* __restrict__ bih1, const float* __restrict__ bhh1,
    const float* __restrict__ Wfc, const float* __restrict__ bfc,
    float* __restrict__ out)
{
    __shared__ float s_x[BR][TC * 3];
    __shared__ float s_h0[2][BR][HP];     // double-buffered layer-0 hidden
    __shared__ float s_h1[BR][HP];        // layer-1 hidden (single buffer: RAW split by barrier)
    __shared__ float s_pre0[4][BR][HD];   // layer-0 gate preacts
    __shared__ float s_pre1[4][BR][HD];   // layer-1 gate preacts

    const int tid = threadIdx.x;
    const int w   = tid >> 6;                 // wave id
    const int j   = tid & 63;                 // lane
    const int jj  = (j < HD) ? j : (HD - 1);  // clamp idle lanes
    const bool isA = (w < 4);                 // waves 0-3: layer 0; 4-7: layer 1
    const int g   = (w & 3) * HD + jj;        // gate-row index in [0,200)
    const int r0  = blockIdx.x * BR;

    // ---- per-lane weights, VGPR-resident for the whole loop ----
    float wk0[HD], wk1[HD];
    float wx0 = 0.f, wx1 = 0.f, wx2 = 0.f, bb = 0.f;
    if (isA) {
        #pragma unroll
        for (int k = 0; k < HD; ++k) wk0[k] = Whh0[g * HD + k];
        wx0 = Wih0[g * 3 + 0];
        wx1 = Wih0[g * 3 + 1];
        wx2 = Wih0[g * 3 + 2];
        bb = bih0[g] + bhh0[g];
    } else {
        #pragma unroll
        for (int k = 0; k < HD; ++k) wk0[k] = Wih1[g * HD + k];
        #pragma unroll
        for (int k = 0; k < HD; ++k) wk1[k] = Whh1[g * HD + k];
        bb = bih1[g] + bhh1[g];
    }

    // ---- c-state lives in registers of the elementwise-owning thread ----
    float c0r[4] = {0.f, 0.f, 0.f, 0.f};  // used by A threads
    float c1r[4] = {0.f, 0.f, 0.f, 0.f};  // used by B threads

    // ---- zero-init h state ----
    for (int p = tid; p < 2 * BR * HP; p += 512) (&s_h0[0][0][0])[p] = 0.f;
    for (int p = tid; p < BR * HP; p += 512) (&s_h1[0][0])[p] = 0.f;
    __syncthreads();

    for (int i = 0; i <= TT; ++i) {       // 513 iterations (pipeline drain at i=TT)
        const int tc = i % TC;
        if (i < TT && tc == 0) {
            // stage x[r0..r0+BR-1][i..i+TC-1][0..2]
            for (int p = tid; p < BR * TC * 3; p += 512) {
                int r = p / (TC * 3);
                int q = p % (TC * 3);
                s_x[r][q] = x[(size_t)(r0 + r) * (TT * 3) + (size_t)i * 3 + q];
            }
            __syncthreads();
        }

        // ================= phase 1: gate pre-activations =================
        if (isA) {
            if (i < TT) {
                const float* hp = &s_h0[(i + 1) & 1][0][0];   // h0[i-1]
                #pragma unroll 2
                for (int r = 0; r < BR; ++r) {
                    float a0 = bb
                             + wx0 * s_x[r][tc * 3 + 0]
                             + wx1 * s_x[r][tc * 3 + 1]
                             + wx2 * s_x[r][tc * 3 + 2];
                    float a1 = 0.f;
                    #pragma unroll
                    for (int k = 0; k < HD; k += 2) {
                        a0 += wk0[k]     * hp[r * HP + k];
                        a1 += wk0[k + 1] * hp[r * HP + k + 1];
                    }
                    if (j < HD) s_pre0[w][r][j] = a0 + a1;
                }
            }
        } else {
            if (i >= 1) {
                const float* hp = &s_h0[(i + 1) & 1][0][0];   // h0[i-1]
                #pragma unroll 2
                for (int r = 0; r < BR; ++r) {
                    float a0 = bb;
                    float a1 = 0.f;
                    #pragma unroll
                    for (int k = 0; k < HD; ++k) {
                        a0 += wk0[k] * hp[r * HP + k];
                        a1 += wk1[k] * s_h1[r][k];
                    }
                    if (j < HD) s_pre1[w - 4][r][j] = a0 + a1;
                }
            }
        }
        __syncthreads();

        // ================= phase 2: elementwise updates =================
        if (isA) {
            if (i < TT) {
                float* hw = &s_h0[i & 1][0][0];               // write h0[i]
                #pragma unroll
                for (int q = 0; q < 4; ++q) {
                    int p = tid + q * 256;
                    if (p < BR * HD) {
                        int r = p / HD, u = p % HD;
                        float iv = sigf(s_pre0[0][r][u]);
                        float fv = sigf(s_pre0[1][r][u]);
                        float gv = tanhfast(s_pre0[2][r][u]);
                        float ov = sigf(s_pre0[3][r][u]);
                        float c = fv * c0r[q] + iv * gv;
                        c0r[q] = c;
                        hw[r * HP + u] = ov * tanhfast(c);
                    }
                }
            }
        } else {
            if (i >= 1) {
                #pragma unroll
                for (int q = 0; q < 4; ++q) {
                    int p = (tid - 256) + q * 256;
                    if (p < BR * HD) {
                        int r = p / HD, u = p % HD;
                        float iv = sigf(s_pre1[0][r][u]);
                        float fv = sigf(s_pre1[1][r][u]);
                        float gv = tanhfast(s_pre1[2][r][u]);
                        float ov = sigf(s_pre1[3][r][u]);
                        float c = fv * c1r[q] + iv * gv;
                        c1r[q] = c;
                        s_h1[r][u] = ov * tanhfast(c);        // h1[i-1]
                    }
                }
            }
        }
        __syncthreads();
    }

    // ---- FC epilogue: out[r][o] = h1[r] . Wfc[o] + bfc[o] ----
    for (int p = tid; p < BR * 7; p += 512) {
        int r = p / 7, o = p % 7;
        float acc = bfc[o];
        #pragma unroll
        for (int k = 0; k < HD; ++k) acc += Wfc[o * HD + k] * s_h1[r][k];
        out[(size_t)(r0 + r) * 7 + o] = acc;
    }
}

extern "C" void kernel_launch(void* const* d_in, const int* in_sizes, int n_in,
                              void* d_out, int out_size, void* d_ws, size_t ws_size,
                              hipStream_t stream) {
    const float* xp    = (const float*)d_in[0];
    const float* Wih0  = (const float*)d_in[1];
    const float* Whh0  = (const float*)d_in[2];
    const float* bih0  = (const float*)d_in[3];
    const float* bhh0  = (const float*)d_in[4];
    const float* Wih1  = (const float*)d_in[5];
    const float* Whh1  = (const float*)d_in[6];
    const float* bih1  = (const float*)d_in[7];
    const float* bhh1  = (const float*)d_in[8];
    const float* Wfc   = (const float*)d_in[9];
    const float* bfc   = (const float*)d_in[10];
    float* outp = (float*)d_out;

    const int B = in_sizes[0] / (TT * 3);   // 4096
    const int grid = B / BR;                // 256 blocks, 1 per CU

    lstm2_pipe_kernel<<<grid, 512, 0, stream>>>(
        xp, Wih0, Whh0, bih0, bhh0, Wih1, Whh1, bih1, bhh1, Wfc, bfc, outp);
}

// Round 4
// 1227.217 us; speedup vs baseline: 4.4063x; 4.4063x over previous
//
#include <hip/hip_runtime.h>
#include <math.h>

#define HD 50
#define NG 200
#define TT 512
#define BRR 16         // batch rows per block -> 256 blocks = 1/CU
#define TC 32          // x prefetch chunk (timesteps)
#define HS 72          // shorts per h row (144B stride -> conflict-free A-frag reads)
#define PS 208         // pre row slots: 4 gate-types * 52

using bf16x8 = __attribute__((ext_vector_type(8))) short;
using f32x4  = __attribute__((ext_vector_type(4))) float;
using s4v    = __attribute__((ext_vector_type(4))) short;
using s2v    = __attribute__((ext_vector_type(2))) short;

__device__ __forceinline__ unsigned short f2bf(float f) {   // RNE float->bf16
    unsigned int u = __float_as_uint(f);
    u += 0x7FFFu + ((u >> 16) & 1u);
    return (unsigned short)(u >> 16);
}
__device__ __forceinline__ float bf2f(unsigned short b) {
    return __uint_as_float(((unsigned int)b) << 16);
}
__device__ __forceinline__ float sigf(float x) { return 1.0f / (1.0f + __expf(-x)); }
__device__ __forceinline__ float tanhfast(float x) { return 1.0f - 2.0f / (__expf(2.0f*x) + 1.0f); }

// 8 waves: w0-3 = layer-0 MFMA (step t), w4-7 = layer-1 MFMA (step t-1).
// Weights as bf16 hi/lo MFMA B-fragments, VGPR-resident all 512 steps.
// 3-term split product: Ahi*Bhi + Alo*Bhi + Ahi*Blo (lo*lo dropped, ~1e-4/preact).
__global__ __launch_bounds__(512, 2) void lstm2_mfma(
    const float* __restrict__ x,
    const float* __restrict__ Wih0, const float* __restrict__ Whh0,
    const float* __restrict__ bih0, const float* __restrict__ bhh0,
    const float* __restrict__ Wih1, const float* __restrict__ Whh1,
    const float* __restrict__ bih1, const float* __restrict__ bhh1,
    const float* __restrict__ Wfc, const float* __restrict__ bfc,
    float* __restrict__ out)
{
    __shared__ float s_pre0[BRR][PS];                 // [row][type*52+u]
    __shared__ float s_pre1[BRR][PS];
    __shared__ short s_h0hi[BRR][HS], s_h0lo[BRR][HS]; // k-slots: 0-49 h, 50-52 x, 53-63 zero
    __shared__ short s_h1hi[BRR][HS], s_h1lo[BRR][HS];
    __shared__ float s_xs[2][BRR][TC*3];

    const int tid  = threadIdx.x;
    const int wid  = tid >> 6;
    const int lane = tid & 63;
    const int lr   = lane & 15;    // M-row (A/D) or N-col (B/D)
    const int lq   = lane >> 4;    // k-octet
    const int r0   = blockIdx.x * BRR;
    const bool pathA = (wid < 4);

    // tile assignment: L0 tiles w0:0-3 w1:4-6 w2:7-9 w3:10-12; L1 w4:0-2 w5:3-5 w6:6-8 w7:9-12
    const int tbase = pathA ? ((wid == 0) ? 0 : 1 + wid*3) : (wid - 4)*3;
    const int tcnt  = pathA ? ((wid == 0) ? 4 : 3) : ((wid == 7) ? 4 : 3);

    // ---- weight B-fragments (hi/lo), VGPR-resident ----
    bf16x8 bh[4][4], bl[4][4];
    int   gT[4]; int slT[4]; float bvT[4];
    #pragma unroll
    for (int tt = 0; tt < 4; ++tt) {
        #pragma unroll
        for (int s = 0; s < 4; ++s) { bh[tt][s] = (bf16x8)0; bl[tt][s] = (bf16x8)0; }
        const int g = (tbase + tt)*16 + lr;
        gT[tt] = g;
        const bool v = (tt < tcnt) && (g < NG);
        slT[tt] = v ? (g/HD)*52 + (g%HD) : 0;
        if (pathA) {
            bvT[tt] = v ? bih0[g] + bhh0[g] : 0.f;
            #pragma unroll
            for (int s = 0; s < 2; ++s) {
                #pragma unroll
                for (int j = 0; j < 8; ++j) {
                    const int k = s*32 + lq*8 + j;
                    float wv = 0.f;
                    if (v) {
                        if (k < HD) wv = Whh0[g*HD + k];
                        else if (k < HD+3) wv = Wih0[g*3 + (k-HD)];
                    }
                    const unsigned short hb = f2bf(wv);
                    bh[tt][s][j] = (short)hb;
                    bl[tt][s][j] = (short)f2bf(wv - bf2f(hb));
                }
            }
        } else {
            bvT[tt] = v ? bih1[g] + bhh1[g] : 0.f;
            #pragma unroll
            for (int s = 0; s < 4; ++s) {
                #pragma unroll
                for (int j = 0; j < 8; ++j) {
                    const int k = s*32 + lq*8 + j;   // 0-63: Wih1 k-space, 64-127: Whh1
                    float wv = 0.f;
                    if (v) {
                        if (k < HD) wv = Wih1[g*HD + k];
                        else if (k >= 64 && k < 64+HD) wv = Whh1[g*HD + (k-64)];
                    }
                    const unsigned short hb = f2bf(wv);
                    bh[tt][s][j] = (short)hb;
                    bl[tt][s][j] = (short)f2bf(wv - bf2f(hb));
                }
            }
        }
    }

    // ---- elementwise ownership: 208 threads, (row, 4-unit block) ----
    const bool ew  = (tid < 208);
    const int  er  = tid / 13;
    const int  eub = (tid % 13) * 4;
    float c0r[4] = {0,0,0,0};
    float c1r[4] = {0,0,0,0};

    // ---- init LDS ----
    for (int p = tid; p < BRR*HS; p += 512) {
        const int rr = p / HS, cc = p % HS;
        s_h0hi[rr][cc] = 0; s_h0lo[rr][cc] = 0;
        s_h1hi[rr][cc] = 0; s_h1lo[rr][cc] = 0;
    }
    for (int p = tid; p < 128; p += 512) {            // zero pre pad slots (u=50,51 per type)
        const int rr = p / 8, ii = p % 8;
        s_pre0[rr][(ii>>1)*52 + 50 + (ii&1)] = 0.f;
        s_pre1[rr][(ii>>1)*52 + 50 + (ii&1)] = 0.f;
    }
    for (int p = tid; p < BRR*TC*3; p += 512) {       // stage x chunk 0
        const int rr = p / (TC*3), q = p % (TC*3);
        s_xs[0][rr][q] = x[(size_t)(r0+rr)*(TT*3) + q];
    }
    __syncthreads();
    if (tid >= 208 && tid < 256) {                    // write x(0) into A0 k-slots 50-52
        const int p = tid - 208; const int rr = p/3, d = p%3;
        const float xv = s_xs[0][rr][d];
        const unsigned short xh = f2bf(xv);
        s_h0hi[rr][HD+d] = (short)xh;
        s_h0lo[rr][HD+d] = (short)f2bf(xv - bf2f(xh));
    }
    __syncthreads();

    // ================= main loop: 513 ticks =================
    for (int n = 0; n <= TT; ++n) {
        // ---------- MFMA phase ----------
        if (pathA) {
            if (n < TT) {                              // pre0(n) = [h0(n-1)|x(n)] @ W0
                bf16x8 a0h[2], a0l[2];
                #pragma unroll
                for (int s = 0; s < 2; ++s) {
                    const int off = lr*(2*HS) + s*64 + lq*16;
                    a0h[s] = *(const bf16x8*)((const char*)&s_h0hi[0][0] + off);
                    a0l[s] = *(const bf16x8*)((const char*)&s_h0lo[0][0] + off);
                }
                f32x4 acc[4];
                #pragma unroll
                for (int tt = 0; tt < 4; ++tt) { const float b = bvT[tt]; acc[tt] = (f32x4){b,b,b,b}; }
                #pragma unroll
                for (int s = 0; s < 2; ++s) {
                    #pragma unroll
                    for (int tt = 0; tt < 4; ++tt) if (tt < tcnt)
                        acc[tt] = __builtin_amdgcn_mfma_f32_16x16x32_bf16(a0h[s], bh[tt][s], acc[tt], 0,0,0);
                    #pragma unroll
                    for (int tt = 0; tt < 4; ++tt) if (tt < tcnt)
                        acc[tt] = __builtin_amdgcn_mfma_f32_16x16x32_bf16(a0l[s], bh[tt][s], acc[tt], 0,0,0);
                    #pragma unroll
                    for (int tt = 0; tt < 4; ++tt) if (tt < tcnt)
                        acc[tt] = __builtin_amdgcn_mfma_f32_16x16x32_bf16(a0h[s], bl[tt][s], acc[tt], 0,0,0);
                }
                #pragma unroll
                for (int tt = 0; tt < 4; ++tt) if (tt < tcnt && gT[tt] < NG) {
                    #pragma unroll
                    for (int j = 0; j < 4; ++j) s_pre0[lq*4+j][slT[tt]] = acc[tt][j];
                }
            }
        } else {
            if (n >= 1) {                              // pre1(n-1) = [h0(n-1)|h1(n-2)] @ W1
                bf16x8 ah[4], al[4];
                #pragma unroll
                for (int s = 0; s < 2; ++s) {
                    const int off = lr*(2*HS) + s*64 + lq*16;
                    ah[s]   = *(const bf16x8*)((const char*)&s_h0hi[0][0] + off);
                    al[s]   = *(const bf16x8*)((const char*)&s_h0lo[0][0] + off);
                    ah[2+s] = *(const bf16x8*)((const char*)&s_h1hi[0][0] + off);
                    al[2+s] = *(const bf16x8*)((const char*)&s_h1lo[0][0] + off);
                }
                f32x4 acc[4];
                #pragma unroll
                for (int tt = 0; tt < 4; ++tt) { const float b = bvT[tt]; acc[tt] = (f32x4){b,b,b,b}; }
                #pragma unroll
                for (int s = 0; s < 4; ++s) {
                    #pragma unroll
                    for (int tt = 0; tt < 4; ++tt) if (tt < tcnt)
                        acc[tt] = __builtin_amdgcn_mfma_f32_16x16x32_bf16(ah[s], bh[tt][s], acc[tt], 0,0,0);
                    #pragma unroll
                    for (int tt = 0; tt < 4; ++tt) if (tt < tcnt)
                        acc[tt] = __builtin_amdgcn_mfma_f32_16x16x32_bf16(al[s], bh[tt][s], acc[tt], 0,0,0);
                    #pragma unroll
                    for (int tt = 0; tt < 4; ++tt) if (tt < tcnt)
                        acc[tt] = __builtin_amdgcn_mfma_f32_16x16x32_bf16(ah[s], bl[tt][s], acc[tt], 0,0,0);
                }
                #pragma unroll
                for (int tt = 0; tt < 4; ++tt) if (tt < tcnt && gT[tt] < NG) {
                    #pragma unroll
                    for (int j = 0; j < 4; ++j) s_pre1[lq*4+j][slT[tt]] = acc[tt][j];
                }
            }
        }
        __syncthreads();

        // ---------- elementwise phase ----------
        if (ew && n < TT) {                            // layer-0 EW: pre0(n) -> h0(n)
            f32x4 pi = *(const f32x4*)&s_pre0[er][0*52 + eub];
            f32x4 pf = *(const f32x4*)&s_pre0[er][1*52 + eub];
            f32x4 pg = *(const f32x4*)&s_pre0[er][2*52 + eub];
            f32x4 po = *(const f32x4*)&s_pre0[er][3*52 + eub];
            short hh[4], hl[4];
            #pragma unroll
            for (int e = 0; e < 4; ++e) {
                const float iv = sigf(pi[e]);
                const float fv = sigf(pf[e]);
                const float gv = tanhfast(pg[e]);
                const float ov = sigf(po[e]);
                const float c  = fv*c0r[e] + iv*gv;
                c0r[e] = c;
                const float h  = ov*tanhfast(c);
                const unsigned short hb = f2bf(h);
                hh[e] = (short)hb; hl[e] = (short)f2bf(h - bf2f(hb));
            }
            if (eub < 48) {
                *(s4v*)&s_h0hi[er][eub] = (s4v){hh[0],hh[1],hh[2],hh[3]};
                *(s4v*)&s_h0lo[er][eub] = (s4v){hl[0],hl[1],hl[2],hl[3]};
            } else {
                *(s2v*)&s_h0hi[er][eub] = (s2v){hh[0],hh[1]};
                *(s2v*)&s_h0lo[er][eub] = (s2v){hl[0],hl[1]};
            }
        }
        if (ew && n >= 1) {                            // layer-1 EW: pre1(n-1) -> h1(n-1)
            f32x4 pi = *(const f32x4*)&s_pre1[er][0*52 + eub];
            f32x4 pf = *(const f32x4*)&s_pre1[er][1*52 + eub];
            f32x4 pg = *(const f32x4*)&s_pre1[er][2*52 + eub];
            f32x4 po = *(const f32x4*)&s_pre1[er][3*52 + eub];
            short hh[4], hl[4];
            #pragma unroll
            for (int e = 0; e < 4; ++e) {
                const float iv = sigf(pi[e]);
                const float fv = sigf(pf[e]);
                const float gv = tanhfast(pg[e]);
                const float ov = sigf(po[e]);
                const float c  = fv*c1r[e] + iv*gv;
                c1r[e] = c;
                const float h  = ov*tanhfast(c);
                const unsigned short hb = f2bf(h);
                hh[e] = (short)hb; hl[e] = (short)f2bf(h - bf2f(hb));
            }
            if (eub < 48) {
                *(s4v*)&s_h1hi[er][eub] = (s4v){hh[0],hh[1],hh[2],hh[3]};
                *(s4v*)&s_h1lo[er][eub] = (s4v){hl[0],hl[1],hl[2],hl[3]};
            } else {
                *(s2v*)&s_h1hi[er][eub] = (s2v){hh[0],hh[1]};
                *(s2v*)&s_h1lo[er][eub] = (s2v){hl[0],hl[1]};
            }
        }
        if (tid >= 208 && tid < 256 && (n+1) < TT) {   // write x(n+1) into A0 k-slots
            const int p = tid - 208; const int rr = p/3, d = p%3;
            const int tn = n + 1;
            const float xv = s_xs[(tn/TC)&1][rr][(tn%TC)*3 + d];
            const unsigned short xh = f2bf(xv);
            s_h0hi[rr][HD+d] = (short)xh;
            s_h0lo[rr][HD+d] = (short)f2bf(xv - bf2f(xh));
        }
        {
            const int t2 = n + 2;                      // stage next x chunk 2 ticks ahead
            if (t2 < TT && (t2 % TC) == 0) {
                const int cb = (t2 / TC) & 1;
                for (int p = tid; p < BRR*TC*3; p += 512) {
                    const int rr = p / (TC*3), q = p % (TC*3);
                    s_xs[cb][rr][q] = x[(size_t)(r0+rr)*(TT*3) + (size_t)t2*3 + q];
                }
            }
        }
        __syncthreads();
    }

    // ---- FC epilogue: out = h1(TT-1) @ Wfc^T + bfc ----
    if (tid < BRR*7) {
        const int r = tid / 7, o = tid % 7;
        float acc = bfc[o];
        #pragma unroll
        for (int u = 0; u < HD; ++u)
            acc += (bf2f((unsigned short)s_h1hi[r][u]) + bf2f((unsigned short)s_h1lo[r][u])) * Wfc[o*HD + u];
        out[(size_t)(r0+r)*7 + o] = acc;
    }
}

extern "C" void kernel_launch(void* const* d_in, const int* in_sizes, int n_in,
                              void* d_out, int out_size, void* d_ws, size_t ws_size,
                              hipStream_t stream) {
    const float* xp    = (const float*)d_in[0];
    const float* Wih0  = (const float*)d_in[1];
    const float* Whh0  = (const float*)d_in[2];
    const float* bih0  = (const float*)d_in[3];
    const float* bhh0  = (const float*)d_in[4];
    const float* Wih1  = (const float*)d_in[5];
    const float* Whh1  = (const float*)d_in[6];
    const float* bih1  = (const float*)d_in[7];
    const float* bhh1  = (const float*)d_in[8];
    const float* Wfc   = (const float*)d_in[9];
    const float* bfc   = (const float*)d_in[10];
    float* outp = (float*)d_out;

    const int B = in_sizes[0] / (TT * 3);   // 4096
    const int grid = B / BRR;               // 256 blocks, 1 per CU

    lstm2_mfma<<<grid, 512, 0, stream>>>(
        xp, Wih0, Whh0, bih0, bhh0, Wih1, Whh1, bih1, bhh1, Wfc, bfc, outp);
}